// Round 10
// baseline (924.903 us; speedup 1.0000x reference)
//
#include <hip/hip_runtime.h>

constexpr int T_  = 1024;
constexpr int D_  = 2048;
constexpr int H_  = 16;
constexpr int HD_ = 128;
constexpr int E_  = 16;
constexpr int IM_ = 1408;
constexpr int IS_ = 5632;

typedef __attribute__((ext_vector_type(8))) short bf16x8;
typedef __attribute__((ext_vector_type(4))) short short4v;
typedef __attribute__((ext_vector_type(4))) float f32x4;

__device__ __forceinline__ short f2bf(float f){
  unsigned u = __builtin_bit_cast(unsigned, f);
  u += 0x7fffu + ((u >> 16) & 1u);          // RNE to bf16 (finite inputs)
  return (short)(u >> 16);
}
__device__ __forceinline__ float bf2f(short s){
  unsigned u = ((unsigned)(unsigned short)s) << 16;
  return __builtin_bit_cast(float, u);
}
__device__ __forceinline__ unsigned cvtpk(float lo, float hi){
  unsigned r;
  asm("v_cvt_pk_bf16_f32 %0, %1, %2" : "=v"(r) : "v"(lo), "v"(hi));
  return r;                                  // [15:0]=bf16(lo), [31:16]=bf16(hi)
}
__device__ __forceinline__ float pk_lo(unsigned h){
  return __builtin_bit_cast(float, h << 16);
}
__device__ __forceinline__ float pk_hi(unsigned h){
  return __builtin_bit_cast(float, h & 0xffff0000u);
}
__device__ __forceinline__ f32x4 mfma16(bf16x8 a, bf16x8 b, f32x4 c){
  return __builtin_amdgcn_mfma_f32_16x16x32_bf16(a, b, c, 0, 0, 0);
}
__device__ __forceinline__ void split3(float f, short& h, short& m, short& l){
  h = f2bf(f); float r = f - bf2f(h);
  m = f2bf(r); l = f2bf(r - bf2f(m));
}
__device__ __forceinline__ void split2(float f, short& h, short& m){
  h = f2bf(f); m = f2bf(f - bf2f(h));
}
__device__ __forceinline__ uint4 mk4(unsigned a, unsigned b, unsigned c, unsigned d){
  uint4 r; r.x=a; r.y=b; r.z=c; r.w=d; return r;
}
#define LGKM0_BAR() do{ asm volatile("s_waitcnt lgkmcnt(0)" ::: "memory"); \
                        __builtin_amdgcn_s_barrier(); }while(0)

// ---------------- sin/cos table ---------------------------------------------
__global__ __launch_bounds__(256) void sctab_kernel(
    const int* __restrict__ pos, float* __restrict__ cst, float* __restrict__ snt)
{
  int idx = blockIdx.x * 256 + threadIdx.x;
  if (idx >= T_ * 64) return;
  int t = idx >> 6, i = idx & 63;
  float invf = (float)pow(10000.0, -(double)i / 64.0);
  float ang  = (float)pos[t] * invf;
  double s, c;
  sincos((double)ang, &s, &c);
  cst[idx] = (float)c; snt[idx] = (float)s;
}

// ---------------- RMSNorm ---------------------------------------------------
__global__ __launch_bounds__(256) void rms_kernel(
    const float* __restrict__ x, const float* __restrict__ w,
    short* __restrict__ o0, short* __restrict__ o1, short* __restrict__ o2,
    short* __restrict__ ob, float* __restrict__ of)
{
  int t = blockIdx.x, tid = threadIdx.x;
  const float* xr = x + (size_t)t * D_;
  float4 va = ((const float4*)xr)[tid*2];
  float4 vb = ((const float4*)xr)[tid*2+1];
  float ss = va.x*va.x + va.y*va.y + va.z*va.z + va.w*va.w
           + vb.x*vb.x + vb.y*vb.y + vb.z*vb.z + vb.w*vb.w;
  for (int o = 32; o; o >>= 1) ss += __shfl_xor(ss, o, 64);
  __shared__ float red[4];
  int lane = tid & 63, wid = tid >> 6;
  if (lane == 0) red[wid] = ss;
  __syncthreads();
  ss = red[0] + red[1] + red[2] + red[3];
  float rs = 1.0f / sqrtf(ss * (1.0f/D_) + 1e-6f);
  float4 wa = ((const float4*)w)[tid*2];
  float4 wb = ((const float4*)w)[tid*2+1];
  float xv[8] = {va.x,va.y,va.z,va.w, vb.x,vb.y,vb.z,vb.w};
  float wv[8] = {wa.x,wa.y,wa.z,wa.w, wb.x,wb.y,wb.z,wb.w};
  size_t base = (size_t)t * D_ + tid*8;
  #pragma unroll
  for (int p = 0; p < 4; ++p){
    float f0 = xv[2*p]   * rs * wv[2*p];
    float f1 = xv[2*p+1] * rs * wv[2*p+1];
    if (o0){
      unsigned h = cvtpk(f0, f1);
      float r0 = f0 - pk_lo(h), r1 = f1 - pk_hi(h);
      unsigned m = cvtpk(r0, r1);
      unsigned l = cvtpk(r0 - pk_lo(m), r1 - pk_hi(m));
      *(unsigned*)&o0[base + 2*p] = h;
      *(unsigned*)&o1[base + 2*p] = m;
      *(unsigned*)&o2[base + 2*p] = l;
    }
    if (ob) *(unsigned*)&ob[base + 2*p] = cvtpk(f0, f1);
    if (of){ of[base + 2*p] = f0; of[base + 2*p + 1] = f1; }
  }
}

// ---------------- prep K: rotate + split2 -> Kp[2][H][T][HD] ---------------
__global__ __launch_bounds__(256) void prepk_kernel(
    const float* __restrict__ qkv, const float* __restrict__ cst,
    const float* __restrict__ snt, short* __restrict__ Kp0, short* __restrict__ Kp1)
{
  int idx = blockIdx.x * 256 + threadIdx.x;     // T*H*8
  int c = idx & 7, t = (idx >> 3) & (T_-1), h = idx >> 13;
  int d0 = c * 8;
  const float* kp = qkv + (size_t)t * (3*D_) + D_ + h*HD_;
  const float* cp = cst + t*64 + d0;
  const float* sp = snt + t*64 + d0;
  unsigned lh[4], ll[4], hh[4], hl[4];
  #pragma unroll
  for (int p = 0; p < 4; ++p){
    float xl0 = kp[d0+2*p],    xh0 = kp[d0+64+2*p];
    float xl1 = kp[d0+2*p+1],  xh1 = kp[d0+64+2*p+1];
    float cv0 = cp[2*p], sv0 = sp[2*p], cv1 = cp[2*p+1], sv1 = sp[2*p+1];
    float rl0 = xl0*cv0 - xh0*sv0, rh0 = xh0*cv0 + xl0*sv0;
    float rl1 = xl1*cv1 - xh1*sv1, rh1 = xh1*cv1 + xl1*sv1;
    unsigned a = cvtpk(rl0, rl1);
    ll[p] = cvtpk(rl0 - pk_lo(a), rl1 - pk_hi(a)); lh[p] = a;
    unsigned b = cvtpk(rh0, rh1);
    hl[p] = cvtpk(rh0 - pk_lo(b), rh1 - pk_hi(b)); hh[p] = b;
  }
  size_t ob = ((size_t)h*T_ + t) * HD_;
  *(uint4*)(Kp0 + ob + d0)      = mk4(lh[0],lh[1],lh[2],lh[3]);
  *(uint4*)(Kp0 + ob + 64 + d0) = mk4(hh[0],hh[1],hh[2],hh[3]);
  *(uint4*)(Kp1 + ob + d0)      = mk4(ll[0],ll[1],ll[2],ll[3]);
  *(uint4*)(Kp1 + ob + 64 + d0) = mk4(hl[0],hl[1],hl[2],hl[3]);
}

// ---------------- prep V: split2 + transpose -> Vp[2][H][HD][T] ------------
__global__ __launch_bounds__(256) void prepv_kernel(
    const float* __restrict__ qkv, short* __restrict__ Vp0, short* __restrict__ Vp1)
{
  __shared__ short Vl[2][128][72];
  int t0 = blockIdx.x * 64, h = blockIdx.y, tid = threadIdx.x;
  int r = tid >> 2, cq = (tid & 3) * 32;
  const float* src = qkv + (size_t)(t0+r) * (3*D_) + 2*D_ + h*HD_ + cq;
  #pragma unroll
  for (int jj = 0; jj < 8; ++jj){
    float4 v = *(const float4*)(src + jj*4);
    float vv[4] = {v.x, v.y, v.z, v.w};
    #pragma unroll
    for (int u = 0; u < 4; ++u){
      int d = cq + jj*4 + u;
      short a, b; split2(vv[u], a, b);
      Vl[0][d][r] = a; Vl[1][d][r] = b;
    }
  }
  __syncthreads();
  int d = tid >> 1, tc = (tid & 1) * 32;
  short* dst0 = Vp0 + ((size_t)h*HD_ + d) * T_ + t0 + tc;
  short* dst1 = Vp1 + ((size_t)h*HD_ + d) * T_ + t0 + tc;
  #pragma unroll
  for (int q = 0; q < 4; ++q){
    *(uint4*)(dst0 + q*8) = *(const uint4*)&Vl[0][d][tc + q*8];
    *(uint4*)(dst1 + q*8) = *(const uint4*)&Vl[1][d][tc + q*8];
  }
}

// ---------------- prep W (o_w): split2 + transpose -> [N][K] planes --------
__global__ __launch_bounds__(256) void prepw_kernel(
    const float* __restrict__ w, short* __restrict__ P0, short* __restrict__ P1)
{
  __shared__ short L0[64][72], L1[64][72];
  int k0 = blockIdx.x * 64, n0 = blockIdx.y * 64;
  int tid = threadIdx.x;
  int r = tid >> 2, cq = (tid & 3) * 16;
  const float* src = w + (size_t)(k0 + r) * D_ + n0 + cq;
  #pragma unroll
  for (int q = 0; q < 4; ++q){
    float4 f = *(const float4*)(src + q*4);
    float fv[4] = {f.x, f.y, f.z, f.w};
    #pragma unroll
    for (int u = 0; u < 4; ++u){
      int n = cq + q*4 + u;
      short a, b; split2(fv[u], a, b);
      L0[n][r] = a; L1[n][r] = b;
    }
  }
  __syncthreads();
  int n = tid >> 2, kq = (tid & 3) * 16;
  short* d0 = P0 + (size_t)(n0 + n) * D_ + k0 + kq;
  short* d1 = P1 + (size_t)(n0 + n) * D_ + k0 + kq;
  *(uint4*)(d0)     = *(const uint4*)&L0[n][kq];
  *(uint4*)(d0 + 8) = *(const uint4*)&L0[n][kq + 8];
  *(uint4*)(d1)     = *(const uint4*)&L1[n][kq];
  *(uint4*)(d1 + 8) = *(const uint4*)&L1[n][kq + 8];
}

// ---------------- Flash attention v2 (unchanged) ---------------------------
__global__ __launch_bounds__(128) void attn_kernel(
    const float* __restrict__ qkv,
    const float* __restrict__ cst, const float* __restrict__ snt,
    const short* __restrict__ Kp0, const short* __restrict__ Kp1,
    const short* __restrict__ Vp0, const short* __restrict__ Vp1,
    short* __restrict__ c0p, short* __restrict__ c1p, short* __restrict__ c2p)
{
  __shared__ __attribute__((aligned(16))) short Ks[2][2][32][128];
  __shared__ __attribute__((aligned(16))) short Vs[2][2][128][40];
  __shared__ __attribute__((aligned(16))) short Ps[3][2][16][40];

  const float SCALE = 0.08838834764831845f;
  const int QW = 3*D_;
  int h = blockIdx.x;
  int ys = blockIdx.y;
  int qt = (ys < 16) ? (ys*2) : ((31-ys)*2 + 1);
  int q0 = qt * 32;
  int tid = threadIdx.x, lane = tid & 63, wq = tid >> 6;
  int lr = lane & 15, kq8 = (lane >> 4) * 8, r4 = (lane >> 4) * 4;

  bf16x8 qfh[4], qfm[4], qfl[4];
  { int qrow = q0 + wq*16 + lr;
    const float* qp = qkv + (size_t)qrow * QW + h*HD_;
    const float* cp = cst + qrow*64;
    const float* sp = snt + qrow*64;
    float x[4][8], cs[2][8], sn[2][8], rot[4][8];
    for (int ks = 0; ks < 4; ++ks)
      for (int j = 0; j < 8; ++j) x[ks][j] = qp[ks*32 + kq8 + j];
    for (int hf = 0; hf < 2; ++hf)
      for (int j = 0; j < 8; ++j){
        cs[hf][j] = cp[hf*32 + kq8 + j];
        sn[hf][j] = sp[hf*32 + kq8 + j];
      }
    for (int j = 0; j < 8; ++j){
      rot[0][j] = x[0][j]*cs[0][j] - x[2][j]*sn[0][j];
      rot[1][j] = x[1][j]*cs[1][j] - x[3][j]*sn[1][j];
      rot[2][j] = x[2][j]*cs[0][j] + x[0][j]*sn[0][j];
      rot[3][j] = x[3][j]*cs[1][j] + x[1][j]*sn[1][j];
    }
    for (int ks = 0; ks < 4; ++ks)
      for (int j = 0; j < 8; ++j){
        short a, b, c; split3(rot[ks][j], a, b, c);
        qfh[ks][j] = a; qfm[ks][j] = b; qfl[ks][j] = c;
      }
  }

  f32x4 acc[8];
  for (int i = 0; i < 8; ++i) acc[i] = f32x4{0.f,0.f,0.f,0.f};
  float mrun[4] = {-1e30f,-1e30f,-1e30f,-1e30f};
  float lrun[4] = {0.f,0.f,0.f,0.f};

  int krow = tid >> 2, kc = (tid & 3) * 32;
  const short* kb0 = Kp0 + ((size_t)h*T_ + krow) * HD_ + kc;
  const short* kb1 = Kp1 + ((size_t)h*T_ + krow) * HD_ + kc;
  const short* vb0 = Vp0 + ((size_t)h*HD_ + tid) * T_;
  const short* vb1 = Vp1 + ((size_t)h*HD_ + tid) * T_;
  int xr = (krow & 7) * 8;

  uint4 kr0[4], kr1[4], vr0[4], vr1[4];
  auto LOAD = [&](int it){
    size_t ko = (size_t)it * 32 * HD_;
    const uint4* p0 = (const uint4*)(kb0 + ko);
    const uint4* p1 = (const uint4*)(kb1 + ko);
    #pragma unroll
    for (int g = 0; g < 4; ++g){ kr0[g] = p0[g]; kr1[g] = p1[g]; }
    const uint4* q0p = (const uint4*)(vb0 + it*32);
    const uint4* q1p = (const uint4*)(vb1 + it*32);
    #pragma unroll
    for (int g = 0; g < 4; ++g){ vr0[g] = q0p[g]; vr1[g] = q1p[g]; }
  };
  auto STORE = [&](int buf){
    #pragma unroll
    for (int g = 0; g < 4; ++g){
      int col = (kc + 8*g) ^ xr;
      *(uint4*)&Ks[buf][0][krow][col] = kr0[g];
      *(uint4*)&Ks[buf][1][krow][col] = kr1[g];
    }
    #pragma unroll
    for (int g = 0; g < 4; ++g){
      *(uint4*)&Vs[buf][0][tid][g*8] = vr0[g];
      *(uint4*)&Vs[buf][1][tid][g*8] = vr1[g];
    }
  };

  int nt = qt + 1;
  LOAD(0); STORE(0);
  if (nt > 1) LOAD(1);
  LGKM0_BAR();

  int cur = 0;
  for (int it = 0; it < nt; ++it){
    if (it + 1 < nt){
      STORE(cur ^ 1);
      if (it + 2 < nt) LOAD(it + 2);
    }
    int kv0 = it * 32;
    int xl = (lr & 7) * 8;
    f32x4 s0 = f32x4{0.f,0.f,0.f,0.f}, s1 = f32x4{0.f,0.f,0.f,0.f};
    #pragma unroll
    for (int ks = 0; ks < 4; ++ks){
      int col = (ks*32 + kq8) ^ xl;
      bf16x8 b0h = *(const bf16x8*)&Ks[cur][0][lr][col];
      bf16x8 b0m = *(const bf16x8*)&Ks[cur][1][lr][col];
      bf16x8 b1h = *(const bf16x8*)&Ks[cur][0][16+lr][col];
      bf16x8 b1m = *(const bf16x8*)&Ks[cur][1][16+lr][col];
      s0 = mfma16(qfh[ks], b0h, s0); s0 = mfma16(qfh[ks], b0m, s0);
      s0 = mfma16(qfm[ks], b0h, s0); s0 = mfma16(qfm[ks], b0m, s0);
      s0 = mfma16(qfl[ks], b0h, s0);
      s1 = mfma16(qfh[ks], b1h, s1); s1 = mfma16(qfh[ks], b1m, s1);
      s1 = mfma16(qfm[ks], b1h, s1); s1 = mfma16(qfm[ks], b1m, s1);
      s1 = mfma16(qfl[ks], b1h, s1);
    }
    float pm[2][4]; float alpha[4];
    for (int r = 0; r < 4; ++r){
      int qr = q0 + wq*16 + r4 + r;
      float x0 = s0[r]*SCALE, x1 = s1[r]*SCALE;
      if (kv0 + lr > qr)      x0 = -1e30f;
      if (kv0 + 16 + lr > qr) x1 = -1e30f;
      float mt_ = fmaxf(x0, x1);
      mt_ = fmaxf(mt_, __shfl_xor(mt_, 1, 64));
      mt_ = fmaxf(mt_, __shfl_xor(mt_, 2, 64));
      mt_ = fmaxf(mt_, __shfl_xor(mt_, 4, 64));
      mt_ = fmaxf(mt_, __shfl_xor(mt_, 8, 64));
      float mn = fmaxf(mrun[r], mt_);
      float p0 = __expf(x0 - mn), p1 = __expf(x1 - mn);
      pm[0][r] = p0; pm[1][r] = p1;
      float ls = p0 + p1;
      ls += __shfl_xor(ls, 1, 64); ls += __shfl_xor(ls, 2, 64);
      ls += __shfl_xor(ls, 4, 64); ls += __shfl_xor(ls, 8, 64);
      alpha[r] = __expf(mrun[r] - mn);
      lrun[r] = lrun[r]*alpha[r] + ls;
      mrun[r] = mn;
    }
    for (int dt = 0; dt < 8; ++dt){
      f32x4 a = acc[dt];
      a[0]*=alpha[0]; a[1]*=alpha[1]; a[2]*=alpha[2]; a[3]*=alpha[3];
      acc[dt] = a;
    }
    for (int nn = 0; nn < 2; ++nn)
      for (int r = 0; r < 4; ++r){
        short a, b, c; split3(pm[nn][r], a, b, c);
        Ps[0][wq][r4+r][nn*16+lr] = a;
        Ps[1][wq][r4+r][nn*16+lr] = b;
        Ps[2][wq][r4+r][nn*16+lr] = c;
      }
    bf16x8 pah = *(const bf16x8*)&Ps[0][wq][lr][kq8];
    bf16x8 pam = *(const bf16x8*)&Ps[1][wq][lr][kq8];
    bf16x8 pal = *(const bf16x8*)&Ps[2][wq][lr][kq8];
    #pragma unroll
    for (int dt = 0; dt < 8; ++dt){
      bf16x8 vbh = *(const bf16x8*)&Vs[cur][0][dt*16+lr][kq8];
      bf16x8 vbm = *(const bf16x8*)&Vs[cur][1][dt*16+lr][kq8];
      acc[dt] = mfma16(pah, vbh, acc[dt]);
      acc[dt] = mfma16(pah, vbm, acc[dt]);
      acc[dt] = mfma16(pam, vbh, acc[dt]);
      acc[dt] = mfma16(pam, vbm, acc[dt]);
      acc[dt] = mfma16(pal, vbh, acc[dt]);
    }
    LGKM0_BAR();
    cur ^= 1;
  }
  for (int dt = 0; dt < 8; ++dt)
    for (int r = 0; r < 4; ++r){
      int qr = q0 + wq*16 + r4 + r;
      float o = acc[dt][r] / lrun[r];
      size_t ix = (size_t)qr * D_ + h*HD_ + dt*16 + lr;
      short a, b, c; split3(o, a, b, c);
      c0p[ix] = a; c1p[ix] = b; c2p[ix] = c;
    }
}

// ---------------- GEMM modes ----------------------------------------------
enum { M_QKV = 0, M_OPROJ = 1 };

// ------- Pipelined split GEMM: depth-2 B prefetch, depth-1 A ---------------
template<int MODE>
__global__ __launch_bounds__(256) void gemm3_kernel(
    const short* __restrict__ A0, const short* __restrict__ A1, const short* __restrict__ A2,
    const float* __restrict__ Bw,
    const short* __restrict__ Bp0, const short* __restrict__ Bp1,
    const float* __restrict__ bias, const float* __restrict__ addsrc,
    float* __restrict__ outF,
    int K, int lda, int ldb, int ldo)
{
  __shared__ __attribute__((aligned(16))) short As[2][3][64][40];
  __shared__ __attribute__((aligned(16))) short Bs[2][2][64][40];

  int m0 = blockIdx.y * 64, n0 = blockIdx.x * 64;
  int tid = threadIdx.x, lane = tid & 63, wid = tid >> 6;
  int wm = wid >> 1, wn = wid & 1;
  int lr = lane & 15, kq8 = (lane >> 4) * 8;

  f32x4 acc[2][2];
  for (int i = 0; i < 2; ++i)
    for (int j = 0; j < 2; ++j) acc[i][j] = f32x4{0.f,0.f,0.f,0.f};

  int arow = tid >> 2, ac = (tid & 3) * 8;
  const short* aP0 = A0 + (size_t)(m0 + arow) * lda + ac;
  const short* aP1 = A1 + (size_t)(m0 + arow) * lda + ac;
  const short* aP2 = A2 + (size_t)(m0 + arow) * lda + ac;
  int bn = tid & 63, bk0 = (tid >> 6) * 8;
  const float* bP  = Bw  ? (Bw + n0 + bn) : nullptr;
  const short* bq0 = Bp0 ? (Bp0 + (size_t)(n0 + bn) * K) : nullptr;
  const short* bq1 = Bp1 ? (Bp1 + (size_t)(n0 + bn) * K) : nullptr;

  uint4 ar0, ar1, ar2;
  float br_0[8], br_1[8];
  uint4 pb0_0, pb1_0, pb0_1, pb1_1;

  auto LOADA = [&](int kt){
    ar0 = *(const uint4*)(aP0 + kt*32);
    ar1 = *(const uint4*)(aP1 + kt*32);
    ar2 = *(const uint4*)(aP2 + kt*32);
  };
  auto LOADB0 = [&](int kt){
    if constexpr (MODE == M_QKV){
      const float* p = bP + (size_t)(kt*32 + bk0) * ldb;
      #pragma unroll
      for (int j = 0; j < 8; ++j) br_0[j] = p[(size_t)j * ldb];
    } else {
      pb0_0 = *(const uint4*)(bq0 + kt*32 + bk0);
      pb1_0 = *(const uint4*)(bq1 + kt*32 + bk0);
    }
  };
  auto LOADB1 = [&](int kt){
    if constexpr (MODE == M_QKV){
      const float* p = bP + (size_t)(kt*32 + bk0) * ldb;
      #pragma unroll
      for (int j = 0; j < 8; ++j) br_1[j] = p[(size_t)j * ldb];
    } else {
      pb0_1 = *(const uint4*)(bq0 + kt*32 + bk0);
      pb1_1 = *(const uint4*)(bq1 + kt*32 + bk0);
    }
  };
  auto STOREA = [&](int buf){
    *(uint4*)&As[buf][0][arow][ac] = ar0;
    *(uint4*)&As[buf][1][arow][ac] = ar1;
    *(uint4*)&As[buf][2][arow][ac] = ar2;
  };
  auto STOREB0 = [&](int buf){
    if constexpr (MODE == M_QKV){
      unsigned hh[4], mm[4];
      #pragma unroll
      for (int p = 0; p < 4; ++p){
        unsigned h = cvtpk(br_0[2*p], br_0[2*p+1]);
        mm[p] = cvtpk(br_0[2*p] - pk_lo(h), br_0[2*p+1] - pk_hi(h));
        hh[p] = h;
      }
      *(uint4*)&Bs[buf][0][bn][bk0] = mk4(hh[0],hh[1],hh[2],hh[3]);
      *(uint4*)&Bs[buf][1][bn][bk0] = mk4(mm[0],mm[1],mm[2],mm[3]);
    } else {
      *(uint4*)&Bs[buf][0][bn][bk0] = pb0_0;
      *(uint4*)&Bs[buf][1][bn][bk0] = pb1_0;
    }
  };
  auto STOREB1 = [&](int buf){
    if constexpr (MODE == M_QKV){
      unsigned hh[4], mm[4];
      #pragma unroll
      for (int p = 0; p < 4; ++p){
        unsigned h = cvtpk(br_1[2*p], br_1[2*p+1]);
        mm[p] = cvtpk(br_1[2*p] - pk_lo(h), br_1[2*p+1] - pk_hi(h));
        hh[p] = h;
      }
      *(uint4*)&Bs[buf][0][bn][bk0] = mk4(hh[0],hh[1],hh[2],hh[3]);
      *(uint4*)&Bs[buf][1][bn][bk0] = mk4(mm[0],mm[1],mm[2],mm[3]);
    } else {
      *(uint4*)&Bs[buf][0][bn][bk0] = pb0_1;
      *(uint4*)&Bs[buf][1][bn][bk0] = pb1_1;
    }
  };
  auto COMPUTE = [&](int cur){
    bf16x8 aH[2], aM[2], aL[2];
    #pragma unroll
    for (int mt = 0; mt < 2; ++mt){
      aH[mt] = *(const bf16x8*)&As[cur][0][wm*32 + mt*16 + lr][kq8];
      aM[mt] = *(const bf16x8*)&As[cur][1][wm*32 + mt*16 + lr][kq8];
      aL[mt] = *(const bf16x8*)&As[cur][2][wm*32 + mt*16 + lr][kq8];
    }
    #pragma unroll
    for (int nt = 0; nt < 2; ++nt){
      bf16x8 bH = *(const bf16x8*)&Bs[cur][0][wn*32 + nt*16 + lr][kq8];
      bf16x8 bM = *(const bf16x8*)&Bs[cur][1][wn*32 + nt*16 + lr][kq8];
      #pragma unroll
      for (int mt = 0; mt < 2; ++mt){
        f32x4 a = acc[mt][nt];
        a = mfma16(aH[mt], bH, a);
        a = mfma16(aH[mt], bM, a);
        a = mfma16(aM[mt], bH, a);
        a = mfma16(aM[mt], bM, a);
        a = mfma16(aL[mt], bH, a);
        acc[mt][nt] = a;
      }
    }
  };

  int NK = K / 32;   // even, >= 4
  LOADA(0); LOADB0(0);
  STOREA(0); STOREB0(0);
  LOADA(1); LOADB1(1); LOADB0(2);
  LGKM0_BAR();

  int cur = 0;
  for (int kt = 0; kt < NK; kt += 2){
    // even: tile kt in cur; stage kt+1 (A regs + B set1)
    if (kt + 1 < NK){
      STOREA(cur ^ 1); STOREB1(cur ^ 1);
      if (kt + 2 < NK) LOADA(kt + 2);
      if (kt + 3 < NK) LOADB1(kt + 3);
    }
    COMPUTE(cur);
    LGKM0_BAR();
    cur ^= 1;
    // odd: tile kt+1 in cur; stage kt+2 (A regs + B set0)
    if (kt + 2 < NK){
      STOREA(cur ^ 1); STOREB0(cur ^ 1);
      if (kt + 3 < NK) LOADA(kt + 3);
      if (kt + 4 < NK) LOADB0(kt + 4);
    }
    if (kt + 1 < NK){
      COMPUTE(cur);
      LGKM0_BAR();
      cur ^= 1;
    }
  }

  for (int mt = 0; mt < 2; ++mt)
    for (int nt = 0; nt < 2; ++nt)
      for (int r = 0; r < 4; ++r){
        int mrow = m0 + wm*32 + mt*16 + (lane >> 4)*4 + r;
        int col  = n0 + wn*32 + nt*16 + lr;
        float v = acc[mt][nt][r];
        if constexpr (MODE == M_QKV){
          outF[(size_t)mrow * ldo + col] = v + bias[col];
        } else {
          outF[(size_t)mrow * ldo + col] = v + addsrc[(size_t)mrow * ldo + col];
        }
      }
}

// ------- Merged gate/up GEMM: BM=128, depth-2 B prefetch --------------------
__global__ __launch_bounds__(256) void gu_kernel(
    const short* __restrict__ x2b,
    const float* __restrict__ w_gate, const float* __restrict__ w_up,
    const float* __restrict__ sh_gu,
    short* __restrict__ gbuf, short* __restrict__ sbuf,
    const int* __restrict__ perm, const int* __restrict__ offE,
    const int* __restrict__ cntE)
{
  __shared__ __attribute__((aligned(16))) short As[2][128][40];
  __shared__ __attribute__((aligned(16))) short Bs[2][2][64][40];

  int z = blockIdx.z;
  bool SH = (z == E_);
  int N    = SH ? IS_ : IM_;
  int n0 = blockIdx.x * 64;
  if (n0 >= N) return;
  int mcnt  = SH ? T_ : cntE[z];
  int mbase = SH ? 0  : offE[z];
  int m0 = blockIdx.y * 128;
  if (m0 >= mcnt) return;
  int ldb = SH ? 2*IS_ : IM_;
  int ldo = SH ? IS_   : IM_;
  const float* Bg = SH ? sh_gu         : (w_gate + (size_t)z * D_ * IM_);
  const float* Bu = SH ? (sh_gu + IS_) : (w_up   + (size_t)z * D_ * IM_);
  short* outB = SH ? sbuf : gbuf;

  int tid = threadIdx.x, lane = tid & 63, wid = tid >> 6;
  int wm = wid >> 1, wn = wid & 1;
  int lr = lane & 15, kq8 = (lane >> 4) * 8;

  f32x4 acc0[4][2], acc1[4][2];
  #pragma unroll
  for (int i = 0; i < 4; ++i)
    for (int j = 0; j < 2; ++j){
      acc0[i][j] = f32x4{0.f,0.f,0.f,0.f};
      acc1[i][j] = f32x4{0.f,0.f,0.f,0.f};
    }

  int arow = tid >> 1, acol = (tid & 1) * 16;
  int aRowIdx;
  { int mr = m0 + arow;
    int mc = (mr < mcnt) ? mr : 0;
    aRowIdx = SH ? mc : perm[mbase + mc];
  }
  const short* aP = x2b + (size_t)aRowIdx * D_;

  int bn_ = tid & 63, bkq = (tid >> 6) * 8;
  const float* bP0 = Bg + n0 + bn_;
  const float* bP1 = Bu + n0 + bn_;

  uint4 arA, arB;
  float br0_0[8], br1_0[8];   // set0: gate, up
  float br0_1[8], br1_1[8];   // set1

  auto LOADA = [&](int kt){
    const uint4* s = (const uint4*)(aP + kt*32 + acol);
    arA = s[0]; arB = s[1];
  };
  auto LOADB0 = [&](int kt){
    const float* p0 = bP0 + (size_t)(kt*32 + bkq) * ldb;
    const float* p1 = bP1 + (size_t)(kt*32 + bkq) * ldb;
    #pragma unroll
    for (int j = 0; j < 8; ++j){ br0_0[j] = p0[(size_t)j * ldb]; br1_0[j] = p1[(size_t)j * ldb]; }
  };
  auto LOADB1 = [&](int kt){
    const float* p0 = bP0 + (size_t)(kt*32 + bkq) * ldb;
    const float* p1 = bP1 + (size_t)(kt*32 + bkq) * ldb;
    #pragma unroll
    for (int j = 0; j < 8; ++j){ br0_1[j] = p0[(size_t)j * ldb]; br1_1[j] = p1[(size_t)j * ldb]; }
  };
  auto STOREA = [&](int buf){
    *(uint4*)&As[buf][arow][acol]   = arA;
    *(uint4*)&As[buf][arow][acol+8] = arB;
  };
  auto STOREB0 = [&](int buf){
    unsigned v0[4], v1[4];
    #pragma unroll
    for (int p = 0; p < 4; ++p){
      v0[p] = cvtpk(br0_0[2*p], br0_0[2*p+1]);
      v1[p] = cvtpk(br1_0[2*p], br1_0[2*p+1]);
    }
    *(uint4*)&Bs[buf][0][bn_][bkq] = mk4(v0[0],v0[1],v0[2],v0[3]);
    *(uint4*)&Bs[buf][1][bn_][bkq] = mk4(v1[0],v1[1],v1[2],v1[3]);
  };
  auto STOREB1 = [&](int buf){
    unsigned v0[4], v1[4];
    #pragma unroll
    for (int p = 0; p < 4; ++p){
      v0[p] = cvtpk(br0_1[2*p], br0_1[2*p+1]);
      v1[p] = cvtpk(br1_1[2*p], br1_1[2*p+1]);
    }
    *(uint4*)&Bs[buf][0][bn_][bkq] = mk4(v0[0],v0[1],v0[2],v0[3]);
    *(uint4*)&Bs[buf][1][bn_][bkq] = mk4(v1[0],v1[1],v1[2],v1[3]);
  };
  auto COMPUTE = [&](int cur){
    bf16x8 a[4];
    #pragma unroll
    for (int mt = 0; mt < 4; ++mt)
      a[mt] = *(const bf16x8*)&As[cur][wm*64 + mt*16 + lr][kq8];
    #pragma unroll
    for (int nt = 0; nt < 2; ++nt){
      int nrow = wn*32 + nt*16 + lr;
      bf16x8 b0 = *(const bf16x8*)&Bs[cur][0][nrow][kq8];
      bf16x8 b1 = *(const bf16x8*)&Bs[cur][1][nrow][kq8];
      #pragma unroll
      for (int mt = 0; mt < 4; ++mt){
        acc0[mt][nt] = mfma16(a[mt], b0, acc0[mt][nt]);
        acc1[mt][nt] = mfma16(a[mt], b1, acc1[mt][nt]);
      }
    }
  };

  constexpr int NK = D_ / 32;   // 64
  LOADA(0); LOADB0(0);
  STOREA(0); STOREB0(0);
  LOADA(1); LOADB1(1); LOADB0(2);
  LGKM0_BAR();

  int cur = 0;
  for (int kt = 0; kt < NK; kt += 2){
    if (kt + 1 < NK){
      STOREA(cur ^ 1); STOREB1(cur ^ 1);
      if (kt + 2 < NK) LOADA(kt + 2);
      if (kt + 3 < NK) LOADB1(kt + 3);
    }
    COMPUTE(cur);
    LGKM0_BAR();
    cur ^= 1;
    if (kt + 2 < NK){
      STOREA(cur ^ 1); STOREB0(cur ^ 1);
      if (kt + 3 < NK) LOADA(kt + 3);
      if (kt + 4 < NK) LOADB0(kt + 4);
    }
    if (kt + 1 < NK){
      COMPUTE(cur);
      LGKM0_BAR();
      cur ^= 1;
    }
  }

  for (int mt = 0; mt < 4; ++mt)
    for (int nt = 0; nt < 2; ++nt)
      for (int r = 0; r < 4; ++r){
        int mrow = m0 + wm*64 + mt*16 + (lane >> 4)*4 + r;
        if (mrow >= mcnt) continue;
        int col = n0 + wn*32 + nt*16 + lr;
        float v = acc0[mt][nt][r];
        float u = acc1[mt][nt][r];
        float sv = v / (1.f + __expf(-v)) * u;
        outB[(size_t)(mbase + mrow) * ldo + col] = f2bf(sv);
      }
}

// ------- Merged down-proj GEMM: BM=128 + K-split + depth-2 B ----------------
__global__ __launch_bounds__(256) void dn_kernel(
    const short* __restrict__ gbuf, const short* __restrict__ sbuf,
    const float* __restrict__ w_down, const float* __restrict__ sh_down,
    float* __restrict__ outF,
    const int* __restrict__ perm, const int* __restrict__ offE,
    const int* __restrict__ cntE, const float* __restrict__ wgt,
    const float* __restrict__ sig)
{
  __shared__ __attribute__((aligned(16))) short As[2][128][40];
  __shared__ __attribute__((aligned(16))) short Bs[2][64][40];

  int z = blockIdx.z;
  bool SH = (z >= 2*E_);
  int K, kbase, NK, mcnt, mbase;
  const float* Bq;
  const short* Ab;
  if (SH){
    int q = z - 2*E_;                 // 0..3
    K = IS_; kbase = q * (IS_/4); NK = (IS_/4)/32;   // 1408, 44 tiles
    mcnt = T_; mbase = 0;
    Bq = sh_down; Ab = sbuf;
  } else {
    int e = z >> 1, half = z & 1;
    K = IM_; kbase = half * (IM_/2); NK = (IM_/2)/32; // 704, 22 tiles
    mcnt = cntE[e]; mbase = offE[e];
    Bq = w_down + (size_t)e * IM_ * D_; Ab = gbuf;
  }
  int m0 = blockIdx.y * 128;
  if (m0 >= mcnt) return;
  int n0 = blockIdx.x * 64;

  int tid = threadIdx.x, lane = tid & 63, wid = tid >> 6;
  int wm = wid >> 1, wn = wid & 1;
  int lr = lane & 15, kq8 = (lane >> 4) * 8;

  f32x4 acc0[4][2];
  #pragma unroll
  for (int i = 0; i < 4; ++i)
    for (int j = 0; j < 2; ++j) acc0[i][j] = f32x4{0.f,0.f,0.f,0.f};

  int arow = tid >> 1, acol = (tid & 1) * 16;
  int mr = m0 + arow;
  int mc = (mr < mcnt) ? mr : 0;
  const short* aP = Ab + (size_t)(SH ? mc : (mbase + mc)) * K + kbase;

  int bn_ = tid & 63, bkq = (tid >> 6) * 8;
  const float* bP0 = Bq + (size_t)kbase * D_ + n0 + bn_;

  uint4 arA, arB;
  float br_0[8], br_1[8];

  auto LOADA = [&](int kt){
    const uint4* s = (const uint4*)(aP + kt*32 + acol);
    arA = s[0]; arB = s[1];
  };
  auto LOADB0 = [&](int kt){
    const float* p0 = bP0 + (size_t)(kt*32 + bkq) * D_;
    #pragma unroll
    for (int j = 0; j < 8; ++j) br_0[j] = p0[(size_t)j * D_];
  };
  auto LOADB1 = [&](int kt){
    const float* p0 = bP0 + (size_t)(kt*32 + bkq) * D_;
    #pragma unroll
    for (int j = 0; j < 8; ++j) br_1[j] = p0[(size_t)j * D_];
  };
  auto STOREA = [&](int buf){
    *(uint4*)&As[buf][arow][acol]   = arA;
    *(uint4*)&As[buf][arow][acol+8] = arB;
  };
  auto STOREB0 = [&](int buf){
    unsigned v0[4];
    #pragma unroll
    for (int p = 0; p < 4; ++p) v0[p] = cvtpk(br_0[2*p], br_0[2*p+1]);
    *(uint4*)&Bs[buf][bn_][bkq] = mk4(v0[0],v0[1],v0[2],v0[3]);
  };
  auto STOREB1 = [&](int buf){
    unsigned v0[4];
    #pragma unroll
    for (int p = 0; p < 4; ++p) v0[p] = cvtpk(br_1[2*p], br_1[2*p+1]);
    *(uint4*)&Bs[buf][bn_][bkq] = mk4(v0[0],v0[1],v0[2],v0[3]);
  };
  auto COMPUTE = [&](int cur){
    bf16x8 a[4];
    #pragma unroll
    for (int mt = 0; mt < 4; ++mt)
      a[mt] = *(const bf16x8*)&As[cur][wm*64 + mt*16 + lr][kq8];
    #pragma unroll
    for (int nt = 0; nt < 2; ++nt){
      bf16x8 b0 = *(const bf16x8*)&Bs[cur][wn*32 + nt*16 + lr][kq8];
      #pragma unroll
      for (int mt = 0; mt < 4; ++mt)
        acc0[mt][nt] = mfma16(a[mt], b0, acc0[mt][nt]);
    }
  };

  LOADA(0); LOADB0(0);
  STOREA(0); STOREB0(0);
  LOADA(1); LOADB1(1); LOADB0(2);
  LGKM0_BAR();

  int cur = 0;
  for (int kt = 0; kt < NK; kt += 2){
    if (kt + 1 < NK){
      STOREA(cur ^ 1); STOREB1(cur ^ 1);
      if (kt + 2 < NK) LOADA(kt + 2);
      if (kt + 3 < NK) LOADB1(kt + 3);
    }
    COMPUTE(cur);
    LGKM0_BAR();
    cur ^= 1;
    if (kt + 2 < NK){
      STOREA(cur ^ 1); STOREB0(cur ^ 1);
      if (kt + 3 < NK) LOADA(kt + 3);
      if (kt + 4 < NK) LOADB0(kt + 4);
    }
    if (kt + 1 < NK){
      COMPUTE(cur);
      LGKM0_BAR();
      cur ^= 1;
    }
  }

  for (int mt = 0; mt < 4; ++mt)
    for (int nt = 0; nt < 2; ++nt)
      for (int r = 0; r < 4; ++r){
        int mrow = m0 + wm*64 + mt*16 + (lane >> 4)*4 + r;
        if (mrow >= mcnt) continue;
        int col = n0 + wn*32 + nt*16 + lr;
        float v = acc0[mt][nt][r];
        if (SH){
          atomicAdd(&outF[(size_t)mrow * D_ + col], sig[mrow] * v);
        } else {
          int tk = perm[mbase + mrow];
          atomicAdd(&outF[(size_t)tk * D_ + col], v * wgt[mbase + mrow]);
        }
      }
}

// ---------------- Router ---------------------------------------------------
__global__ __launch_bounds__(256) void router_kernel(
    const float* __restrict__ x2f, const float* __restrict__ rw,
    const float* __restrict__ seg, int* __restrict__ te, float* __restrict__ tw,
    float* __restrict__ sig, int* __restrict__ cnt)
{
  int t = blockIdx.x, tid = threadIdx.x, lane = tid & 63, w = tid >> 6;
  const float* xr = x2f + (size_t)t * D_;
  float a0 = 0.f, a1 = 0.f, a2 = 0.f, a3 = 0.f, ag = 0.f;
  for (int j = 0; j < 32; ++j){
    int d = lane + 64*j;
    float xv = xr[d];
    const float* rp = rw + (size_t)d * E_ + w*4;
    a0 += xv * rp[0]; a1 += xv * rp[1]; a2 += xv * rp[2]; a3 += xv * rp[3];
    ag += xv * seg[d];
  }
  for (int o = 32; o; o >>= 1){
    a0 += __shfl_xor(a0, o, 64); a1 += __shfl_xor(a1, o, 64);
    a2 += __shfl_xor(a2, o, 64); a3 += __shfl_xor(a3, o, 64);
    ag += __shfl_xor(ag, o, 64);
  }
  __shared__ float lg[16];
  __shared__ float sgv;
  if (lane == 0){
    lg[w*4+0] = a0; lg[w*4+1] = a1; lg[w*4+2] = a2; lg[w*4+3] = a3;
    if (w == 0) sgv = ag;
  }
  __syncthreads();
  if (tid == 0){
    int e0 = 0; float v0 = lg[0];
    for (int ee = 1; ee < 16; ++ee) if (lg[ee] > v0){ v0 = lg[ee]; e0 = ee; }
    int e1 = -1; float v1 = -3e38f;
    for (int ee = 0; ee < 16; ++ee){
      if (ee == e0) continue;
      if (lg[ee] > v1){ v1 = lg[ee]; e1 = ee; }
    }
    float w0 = 1.f / (1.f + expf(v1 - v0));
    te[2*t] = e0; te[2*t+1] = e1;
    tw[2*t] = w0; tw[2*t+1] = 1.f - w0;
    atomicAdd(&cnt[e0], 1); atomicAdd(&cnt[e1], 1);
    sig[t] = 1.f / (1.f + expf(-sgv));
  }
}

__global__ void prefix_kernel(const int* __restrict__ cnt, int* __restrict__ offE,
                              int* __restrict__ cursor)
{
  if (threadIdx.x == 0){
    int s = 0;
    for (int e = 0; e < 16; ++e){ offE[e] = s; s += cnt[e]; }
  }
  if (threadIdx.x < 16) cursor[threadIdx.x] = 0;
}

__global__ __launch_bounds__(256) void scatter_kernel(
    const int* __restrict__ te, const float* __restrict__ tw,
    const int* __restrict__ offE, int* __restrict__ cursor,
    int* __restrict__ perm, float* __restrict__ wgt)
{
  int t = blockIdx.x * 256 + threadIdx.x;
  if (t >= T_) return;
  for (int i = 0; i < 2; ++i){
    int e = te[2*t + i];
    int pos = offE[e] + atomicAdd(&cursor[e], 1);
    perm[pos] = t; wgt[pos] = tw[2*t + i];
  }
}

// ---------------------------------------------------------------------------
extern "C" void kernel_launch(void* const* d_in, const int* in_sizes, int n_in,
                              void* d_out, int out_size, void* d_ws, size_t ws_size,
                              hipStream_t stream)
{
  const int*   positions = (const int*)  d_in[0];
  const float* hidden    = (const float*)d_in[1];
  const float* ln1       = (const float*)d_in[2];
  const float* ln2       = (const float*)d_in[3];
  const float* qkv_w     = (const float*)d_in[4];
  const float* qkv_b     = (const float*)d_in[5];
  const float* o_w       = (const float*)d_in[6];
  const float* router_w  = (const float*)d_in[7];
  const float* w_gate    = (const float*)d_in[8];
  const float* w_up      = (const float*)d_in[9];
  const float* w_down    = (const float*)d_in[10];
  const float* sh_gu     = (const float*)d_in[11];
  const float* sh_down   = (const float*)d_in[12];
  const float* sh_eg     = (const float*)d_in[13];

  float* out_hidden = (float*)d_out;
  float* out_resid  = (float*)d_out + (size_t)T_ * D_;

  char* wp = (char*)d_ws;
  auto alloc = [&](size_t b){ char* p = wp; wp += (b + 255) & ~(size_t)255; return p; };

  float* qkv  = (float*)alloc((size_t)T_ * 3*D_ * 4);   // 24 MB
  short* x1h  = (short*)alloc((size_t)T_ * D_ * 2);     // 12 MB (3 planes)
  short* x1m  = (short*)alloc((size_t)T_ * D_ * 2);
  short* x1l  = (short*)alloc((size_t)T_ * D_ * 2);
  short* Kp0  = (short*)alloc((size_t)T_ * D_ * 2);     // 16 MB (K/V planes)
  short* Kp1  = (short*)alloc((size_t)T_ * D_ * 2);
  short* Vp0  = (short*)alloc((size_t)T_ * D_ * 2);
  short* Vp1  = (short*)alloc((size_t)T_ * D_ * 2);
  float* cst  = (float*)alloc((size_t)T_ * 64 * 4);
  float* snt  = (float*)alloc((size_t)T_ * 64 * 4);
  int*   te   = (int*)  alloc(2*T_*4);
  float* tw   = (float*)alloc(2*T_*4);
  float* sig  = (float*)alloc(T_*4);
  int*   cnt    = (int*)alloc(256);
  int*   offE   = (int*)alloc(256);
  int*   cursor = (int*)alloc(256);
  int*   perm = (int*)  alloc(2*T_*4);
  float* wgt  = (float*)alloc(2*T_*4);

  // aliases (lifetimes disjoint):
  short* ctxh = x1h;                                    // after QKV GEMM
  short* ctxm = x1m;
  short* ctxl = x1l;
  float* x2f  = qkv;                                    // after attn
  short* sbuf = (short*)((char*)qkv + (size_t)8388608); // after attn
  short* gbuf = (short*)x1h;                            // after OPROJ
  short* x2b  = (short*)((char*)x1h + (size_t)5767168); // after OPROJ
  short* Wo0  = Kp0;                                    // after attn
  short* Wo1  = Vp0;                                    // after attn

  hipMemsetAsync(cnt, 0, 64, stream);
  hipMemsetAsync(out_hidden, 0, (size_t)T_ * D_ * 4, stream);

  sctab_kernel<<<(T_*64)/256, 256, 0, stream>>>(positions, cst, snt);

  rms_kernel<<<T_, 256, 0, stream>>>(hidden, ln1, x1h, x1m, x1l, nullptr, nullptr);

  gemm3_kernel<M_QKV><<<dim3(96, 16), 256, 0, stream>>>(
      x1h, x1m, x1l, qkv_w, nullptr, nullptr, qkv_b, nullptr, qkv,
      D_, D_, 3*D_, 3*D_);

  prepk_kernel<<<(T_*H_*8)/256, 256, 0, stream>>>(qkv, cst, snt, Kp0, Kp1);
  prepv_kernel<<<dim3(16, 16), 256, 0, stream>>>(qkv, Vp0, Vp1);

  attn_kernel<<<dim3(16, 32), 128, 0, stream>>>(
      qkv, cst, snt, Kp0, Kp1, Vp0, Vp1, ctxh, ctxm, ctxl);

  prepw_kernel<<<dim3(32, 32), 256, 0, stream>>>(o_w, Wo0, Wo1);

  gemm3_kernel<M_OPROJ><<<dim3(32, 16), 256, 0, stream>>>(
      ctxh, ctxm, ctxl, nullptr, Wo0, Wo1, nullptr, hidden, out_resid,
      D_, D_, D_, D_);

  rms_kernel<<<T_, 256, 0, stream>>>(out_resid, ln2, nullptr, nullptr, nullptr, x2b, x2f);

  router_kernel<<<T_, 256, 0, stream>>>(x2f, router_w, sh_eg, te, tw, sig, cnt);
  prefix_kernel<<<1, 64, 0, stream>>>(cnt, offE, cursor);
  scatter_kernel<<<4, 256, 0, stream>>>(te, tw, offE, cursor, perm, wgt);

  gu_kernel<<<dim3(88, 8, 17), 256, 0, stream>>>(
      x2b, w_gate, w_up, sh_gu, gbuf, sbuf, perm, offE, cnt);

  dn_kernel<<<dim3(32, 8, 36), 256, 0, stream>>>(
      gbuf, sbuf, w_down, sh_down, out_hidden, perm, offE, cnt, wgt, sig);

  (void)in_sizes; (void)n_in; (void)out_size; (void)ws_size;
}

// Round 11
// 829.021 us; speedup vs baseline: 1.1157x; 1.1157x over previous
//
#include <hip/hip_runtime.h>

constexpr int T_  = 1024;
constexpr int D_  = 2048;
constexpr int H_  = 16;
constexpr int HD_ = 128;
constexpr int E_  = 16;
constexpr int IM_ = 1408;
constexpr int IS_ = 5632;

typedef __attribute__((ext_vector_type(8))) short bf16x8;
typedef __attribute__((ext_vector_type(4))) short short4v;
typedef __attribute__((ext_vector_type(4))) float f32x4;

__device__ __forceinline__ short f2bf(float f){
  unsigned u = __builtin_bit_cast(unsigned, f);
  u += 0x7fffu + ((u >> 16) & 1u);          // RNE to bf16 (finite inputs)
  return (short)(u >> 16);
}
__device__ __forceinline__ float bf2f(short s){
  unsigned u = ((unsigned)(unsigned short)s) << 16;
  return __builtin_bit_cast(float, u);
}
__device__ __forceinline__ unsigned cvtpk(float lo, float hi){
  unsigned r;
  asm("v_cvt_pk_bf16_f32 %0, %1, %2" : "=v"(r) : "v"(lo), "v"(hi));
  return r;                                  // [15:0]=bf16(lo), [31:16]=bf16(hi)
}
__device__ __forceinline__ float pk_lo(unsigned h){
  return __builtin_bit_cast(float, h << 16);
}
__device__ __forceinline__ float pk_hi(unsigned h){
  return __builtin_bit_cast(float, h & 0xffff0000u);
}
__device__ __forceinline__ f32x4 mfma16(bf16x8 a, bf16x8 b, f32x4 c){
  return __builtin_amdgcn_mfma_f32_16x16x32_bf16(a, b, c, 0, 0, 0);
}
__device__ __forceinline__ void split3(float f, short& h, short& m, short& l){
  h = f2bf(f); float r = f - bf2f(h);
  m = f2bf(r); l = f2bf(r - bf2f(m));
}
__device__ __forceinline__ void split2(float f, short& h, short& m){
  h = f2bf(f); m = f2bf(f - bf2f(h));
}
__device__ __forceinline__ uint4 mk4(unsigned a, unsigned b, unsigned c, unsigned d){
  uint4 r; r.x=a; r.y=b; r.z=c; r.w=d; return r;
}
#define LGKM0_BAR() do{ asm volatile("s_waitcnt lgkmcnt(0)" ::: "memory"); \
                        __builtin_amdgcn_s_barrier(); }while(0)

// ---------------- sin/cos table ---------------------------------------------
__global__ __launch_bounds__(256) void sctab_kernel(
    const int* __restrict__ pos, float* __restrict__ cst, float* __restrict__ snt)
{
  int idx = blockIdx.x * 256 + threadIdx.x;
  if (idx >= T_ * 64) return;
  int t = idx >> 6, i = idx & 63;
  float invf = (float)pow(10000.0, -(double)i / 64.0);
  float ang  = (float)pos[t] * invf;
  double s, c;
  sincos((double)ang, &s, &c);
  cst[idx] = (float)c; snt[idx] = (float)s;
}

// ---------------- RMSNorm ---------------------------------------------------
__global__ __launch_bounds__(256) void rms_kernel(
    const float* __restrict__ x, const float* __restrict__ w,
    short* __restrict__ o0, short* __restrict__ o1, short* __restrict__ o2,
    short* __restrict__ ob, float* __restrict__ of)
{
  int t = blockIdx.x, tid = threadIdx.x;
  const float* xr = x + (size_t)t * D_;
  float4 va = ((const float4*)xr)[tid*2];
  float4 vb = ((const float4*)xr)[tid*2+1];
  float ss = va.x*va.x + va.y*va.y + va.z*va.z + va.w*va.w
           + vb.x*vb.x + vb.y*vb.y + vb.z*vb.z + vb.w*vb.w;
  for (int o = 32; o; o >>= 1) ss += __shfl_xor(ss, o, 64);
  __shared__ float red[4];
  int lane = tid & 63, wid = tid >> 6;
  if (lane == 0) red[wid] = ss;
  __syncthreads();
  ss = red[0] + red[1] + red[2] + red[3];
  float rs = 1.0f / sqrtf(ss * (1.0f/D_) + 1e-6f);
  float4 wa = ((const float4*)w)[tid*2];
  float4 wb = ((const float4*)w)[tid*2+1];
  float xv[8] = {va.x,va.y,va.z,va.w, vb.x,vb.y,vb.z,vb.w};
  float wv[8] = {wa.x,wa.y,wa.z,wa.w, wb.x,wb.y,wb.z,wb.w};
  size_t base = (size_t)t * D_ + tid*8;
  #pragma unroll
  for (int p = 0; p < 4; ++p){
    float f0 = xv[2*p]   * rs * wv[2*p];
    float f1 = xv[2*p+1] * rs * wv[2*p+1];
    if (o0){
      unsigned h = cvtpk(f0, f1);
      float r0 = f0 - pk_lo(h), r1 = f1 - pk_hi(h);
      unsigned m = cvtpk(r0, r1);
      unsigned l = cvtpk(r0 - pk_lo(m), r1 - pk_hi(m));
      *(unsigned*)&o0[base + 2*p] = h;
      *(unsigned*)&o1[base + 2*p] = m;
      *(unsigned*)&o2[base + 2*p] = l;
    }
    if (ob) *(unsigned*)&ob[base + 2*p] = cvtpk(f0, f1);
    if (of){ of[base + 2*p] = f0; of[base + 2*p + 1] = f1; }
  }
}

// ---------------- prep K: rotate + split2 -> Kp[2][H][T][HD] ---------------
__global__ __launch_bounds__(256) void prepk_kernel(
    const float* __restrict__ qkv, const float* __restrict__ cst,
    const float* __restrict__ snt, short* __restrict__ Kp0, short* __restrict__ Kp1)
{
  int idx = blockIdx.x * 256 + threadIdx.x;     // T*H*8
  int c = idx & 7, t = (idx >> 3) & (T_-1), h = idx >> 13;
  int d0 = c * 8;
  const float* kp = qkv + (size_t)t * (3*D_) + D_ + h*HD_;
  const float* cp = cst + t*64 + d0;
  const float* sp = snt + t*64 + d0;
  unsigned lh[4], ll[4], hh[4], hl[4];
  #pragma unroll
  for (int p = 0; p < 4; ++p){
    float xl0 = kp[d0+2*p],    xh0 = kp[d0+64+2*p];
    float xl1 = kp[d0+2*p+1],  xh1 = kp[d0+64+2*p+1];
    float cv0 = cp[2*p], sv0 = sp[2*p], cv1 = cp[2*p+1], sv1 = sp[2*p+1];
    float rl0 = xl0*cv0 - xh0*sv0, rh0 = xh0*cv0 + xl0*sv0;
    float rl1 = xl1*cv1 - xh1*sv1, rh1 = xh1*cv1 + xl1*sv1;
    unsigned a = cvtpk(rl0, rl1);
    ll[p] = cvtpk(rl0 - pk_lo(a), rl1 - pk_hi(a)); lh[p] = a;
    unsigned b = cvtpk(rh0, rh1);
    hl[p] = cvtpk(rh0 - pk_lo(b), rh1 - pk_hi(b)); hh[p] = b;
  }
  size_t ob = ((size_t)h*T_ + t) * HD_;
  *(uint4*)(Kp0 + ob + d0)      = mk4(lh[0],lh[1],lh[2],lh[3]);
  *(uint4*)(Kp0 + ob + 64 + d0) = mk4(hh[0],hh[1],hh[2],hh[3]);
  *(uint4*)(Kp1 + ob + d0)      = mk4(ll[0],ll[1],ll[2],ll[3]);
  *(uint4*)(Kp1 + ob + 64 + d0) = mk4(hl[0],hl[1],hl[2],hl[3]);
}

// ---------------- prep V: split2 + transpose -> Vp[2][H][HD][T] ------------
__global__ __launch_bounds__(256) void prepv_kernel(
    const float* __restrict__ qkv, short* __restrict__ Vp0, short* __restrict__ Vp1)
{
  __shared__ short Vl[2][128][72];
  int t0 = blockIdx.x * 64, h = blockIdx.y, tid = threadIdx.x;
  int r = tid >> 2, cq = (tid & 3) * 32;
  const float* src = qkv + (size_t)(t0+r) * (3*D_) + 2*D_ + h*HD_ + cq;
  #pragma unroll
  for (int jj = 0; jj < 8; ++jj){
    float4 v = *(const float4*)(src + jj*4);
    float vv[4] = {v.x, v.y, v.z, v.w};
    #pragma unroll
    for (int u = 0; u < 4; ++u){
      int d = cq + jj*4 + u;
      short a, b; split2(vv[u], a, b);
      Vl[0][d][r] = a; Vl[1][d][r] = b;
    }
  }
  __syncthreads();
  int d = tid >> 1, tc = (tid & 1) * 32;
  short* dst0 = Vp0 + ((size_t)h*HD_ + d) * T_ + t0 + tc;
  short* dst1 = Vp1 + ((size_t)h*HD_ + d) * T_ + t0 + tc;
  #pragma unroll
  for (int q = 0; q < 4; ++q){
    *(uint4*)(dst0 + q*8) = *(const uint4*)&Vl[0][d][tc + q*8];
    *(uint4*)(dst1 + q*8) = *(const uint4*)&Vl[1][d][tc + q*8];
  }
}

// ---------------- prep W (o_w): split2 + transpose -> [N][K] planes --------
__global__ __launch_bounds__(256) void prepw_kernel(
    const float* __restrict__ w, short* __restrict__ P0, short* __restrict__ P1)
{
  __shared__ short L0[64][72], L1[64][72];
  int k0 = blockIdx.x * 64, n0 = blockIdx.y * 64;
  int tid = threadIdx.x;
  int r = tid >> 2, cq = (tid & 3) * 16;
  const float* src = w + (size_t)(k0 + r) * D_ + n0 + cq;
  #pragma unroll
  for (int q = 0; q < 4; ++q){
    float4 f = *(const float4*)(src + q*4);
    float fv[4] = {f.x, f.y, f.z, f.w};
    #pragma unroll
    for (int u = 0; u < 4; ++u){
      int n = cq + q*4 + u;
      short a, b; split2(fv[u], a, b);
      L0[n][r] = a; L1[n][r] = b;
    }
  }
  __syncthreads();
  int n = tid >> 2, kq = (tid & 3) * 16;
  short* d0 = P0 + (size_t)(n0 + n) * D_ + k0 + kq;
  short* d1 = P1 + (size_t)(n0 + n) * D_ + k0 + kq;
  *(uint4*)(d0)     = *(const uint4*)&L0[n][kq];
  *(uint4*)(d0 + 8) = *(const uint4*)&L0[n][kq + 8];
  *(uint4*)(d1)     = *(const uint4*)&L1[n][kq];
  *(uint4*)(d1 + 8) = *(const uint4*)&L1[n][kq + 8];
}

// ---------------- Flash attention v2 (unchanged) ---------------------------
__global__ __launch_bounds__(128) void attn_kernel(
    const float* __restrict__ qkv,
    const float* __restrict__ cst, const float* __restrict__ snt,
    const short* __restrict__ Kp0, const short* __restrict__ Kp1,
    const short* __restrict__ Vp0, const short* __restrict__ Vp1,
    short* __restrict__ c0p, short* __restrict__ c1p, short* __restrict__ c2p)
{
  __shared__ __attribute__((aligned(16))) short Ks[2][2][32][128];
  __shared__ __attribute__((aligned(16))) short Vs[2][2][128][40];
  __shared__ __attribute__((aligned(16))) short Ps[3][2][16][40];

  const float SCALE = 0.08838834764831845f;
  const int QW = 3*D_;
  int h = blockIdx.x;
  int ys = blockIdx.y;
  int qt = (ys < 16) ? (ys*2) : ((31-ys)*2 + 1);
  int q0 = qt * 32;
  int tid = threadIdx.x, lane = tid & 63, wq = tid >> 6;
  int lr = lane & 15, kq8 = (lane >> 4) * 8, r4 = (lane >> 4) * 4;

  bf16x8 qfh[4], qfm[4], qfl[4];
  { int qrow = q0 + wq*16 + lr;
    const float* qp = qkv + (size_t)qrow * QW + h*HD_;
    const float* cp = cst + qrow*64;
    const float* sp = snt + qrow*64;
    float x[4][8], cs[2][8], sn[2][8], rot[4][8];
    for (int ks = 0; ks < 4; ++ks)
      for (int j = 0; j < 8; ++j) x[ks][j] = qp[ks*32 + kq8 + j];
    for (int hf = 0; hf < 2; ++hf)
      for (int j = 0; j < 8; ++j){
        cs[hf][j] = cp[hf*32 + kq8 + j];
        sn[hf][j] = sp[hf*32 + kq8 + j];
      }
    for (int j = 0; j < 8; ++j){
      rot[0][j] = x[0][j]*cs[0][j] - x[2][j]*sn[0][j];
      rot[1][j] = x[1][j]*cs[1][j] - x[3][j]*sn[1][j];
      rot[2][j] = x[2][j]*cs[0][j] + x[0][j]*sn[0][j];
      rot[3][j] = x[3][j]*cs[1][j] + x[1][j]*sn[1][j];
    }
    for (int ks = 0; ks < 4; ++ks)
      for (int j = 0; j < 8; ++j){
        short a, b, c; split3(rot[ks][j], a, b, c);
        qfh[ks][j] = a; qfm[ks][j] = b; qfl[ks][j] = c;
      }
  }

  f32x4 acc[8];
  for (int i = 0; i < 8; ++i) acc[i] = f32x4{0.f,0.f,0.f,0.f};
  float mrun[4] = {-1e30f,-1e30f,-1e30f,-1e30f};
  float lrun[4] = {0.f,0.f,0.f,0.f};

  int krow = tid >> 2, kc = (tid & 3) * 32;
  const short* kb0 = Kp0 + ((size_t)h*T_ + krow) * HD_ + kc;
  const short* kb1 = Kp1 + ((size_t)h*T_ + krow) * HD_ + kc;
  const short* vb0 = Vp0 + ((size_t)h*HD_ + tid) * T_;
  const short* vb1 = Vp1 + ((size_t)h*HD_ + tid) * T_;
  int xr = (krow & 7) * 8;

  uint4 kr0[4], kr1[4], vr0[4], vr1[4];
  auto LOAD = [&](int it){
    size_t ko = (size_t)it * 32 * HD_;
    const uint4* p0 = (const uint4*)(kb0 + ko);
    const uint4* p1 = (const uint4*)(kb1 + ko);
    #pragma unroll
    for (int g = 0; g < 4; ++g){ kr0[g] = p0[g]; kr1[g] = p1[g]; }
    const uint4* q0p = (const uint4*)(vb0 + it*32);
    const uint4* q1p = (const uint4*)(vb1 + it*32);
    #pragma unroll
    for (int g = 0; g < 4; ++g){ vr0[g] = q0p[g]; vr1[g] = q1p[g]; }
  };
  auto STORE = [&](int buf){
    #pragma unroll
    for (int g = 0; g < 4; ++g){
      int col = (kc + 8*g) ^ xr;
      *(uint4*)&Ks[buf][0][krow][col] = kr0[g];
      *(uint4*)&Ks[buf][1][krow][col] = kr1[g];
    }
    #pragma unroll
    for (int g = 0; g < 4; ++g){
      *(uint4*)&Vs[buf][0][tid][g*8] = vr0[g];
      *(uint4*)&Vs[buf][1][tid][g*8] = vr1[g];
    }
  };

  int nt = qt + 1;
  LOAD(0); STORE(0);
  if (nt > 1) LOAD(1);
  LGKM0_BAR();

  int cur = 0;
  for (int it = 0; it < nt; ++it){
    if (it + 1 < nt){
      STORE(cur ^ 1);
      if (it + 2 < nt) LOAD(it + 2);
    }
    int kv0 = it * 32;
    int xl = (lr & 7) * 8;
    f32x4 s0 = f32x4{0.f,0.f,0.f,0.f}, s1 = f32x4{0.f,0.f,0.f,0.f};
    #pragma unroll
    for (int ks = 0; ks < 4; ++ks){
      int col = (ks*32 + kq8) ^ xl;
      bf16x8 b0h = *(const bf16x8*)&Ks[cur][0][lr][col];
      bf16x8 b0m = *(const bf16x8*)&Ks[cur][1][lr][col];
      bf16x8 b1h = *(const bf16x8*)&Ks[cur][0][16+lr][col];
      bf16x8 b1m = *(const bf16x8*)&Ks[cur][1][16+lr][col];
      s0 = mfma16(qfh[ks], b0h, s0); s0 = mfma16(qfh[ks], b0m, s0);
      s0 = mfma16(qfm[ks], b0h, s0); s0 = mfma16(qfm[ks], b0m, s0);
      s0 = mfma16(qfl[ks], b0h, s0);
      s1 = mfma16(qfh[ks], b1h, s1); s1 = mfma16(qfh[ks], b1m, s1);
      s1 = mfma16(qfm[ks], b1h, s1); s1 = mfma16(qfm[ks], b1m, s1);
      s1 = mfma16(qfl[ks], b1h, s1);
    }
    float pm[2][4]; float alpha[4];
    for (int r = 0; r < 4; ++r){
      int qr = q0 + wq*16 + r4 + r;
      float x0 = s0[r]*SCALE, x1 = s1[r]*SCALE;
      if (kv0 + lr > qr)      x0 = -1e30f;
      if (kv0 + 16 + lr > qr) x1 = -1e30f;
      float mt_ = fmaxf(x0, x1);
      mt_ = fmaxf(mt_, __shfl_xor(mt_, 1, 64));
      mt_ = fmaxf(mt_, __shfl_xor(mt_, 2, 64));
      mt_ = fmaxf(mt_, __shfl_xor(mt_, 4, 64));
      mt_ = fmaxf(mt_, __shfl_xor(mt_, 8, 64));
      float mn = fmaxf(mrun[r], mt_);
      float p0 = __expf(x0 - mn), p1 = __expf(x1 - mn);
      pm[0][r] = p0; pm[1][r] = p1;
      float ls = p0 + p1;
      ls += __shfl_xor(ls, 1, 64); ls += __shfl_xor(ls, 2, 64);
      ls += __shfl_xor(ls, 4, 64); ls += __shfl_xor(ls, 8, 64);
      alpha[r] = __expf(mrun[r] - mn);
      lrun[r] = lrun[r]*alpha[r] + ls;
      mrun[r] = mn;
    }
    for (int dt = 0; dt < 8; ++dt){
      f32x4 a = acc[dt];
      a[0]*=alpha[0]; a[1]*=alpha[1]; a[2]*=alpha[2]; a[3]*=alpha[3];
      acc[dt] = a;
    }
    for (int nn = 0; nn < 2; ++nn)
      for (int r = 0; r < 4; ++r){
        short a, b, c; split3(pm[nn][r], a, b, c);
        Ps[0][wq][r4+r][nn*16+lr] = a;
        Ps[1][wq][r4+r][nn*16+lr] = b;
        Ps[2][wq][r4+r][nn*16+lr] = c;
      }
    bf16x8 pah = *(const bf16x8*)&Ps[0][wq][lr][kq8];
    bf16x8 pam = *(const bf16x8*)&Ps[1][wq][lr][kq8];
    bf16x8 pal = *(const bf16x8*)&Ps[2][wq][lr][kq8];
    #pragma unroll
    for (int dt = 0; dt < 8; ++dt){
      bf16x8 vbh = *(const bf16x8*)&Vs[cur][0][dt*16+lr][kq8];
      bf16x8 vbm = *(const bf16x8*)&Vs[cur][1][dt*16+lr][kq8];
      acc[dt] = mfma16(pah, vbh, acc[dt]);
      acc[dt] = mfma16(pah, vbm, acc[dt]);
      acc[dt] = mfma16(pam, vbh, acc[dt]);
      acc[dt] = mfma16(pam, vbm, acc[dt]);
      acc[dt] = mfma16(pal, vbh, acc[dt]);
    }
    LGKM0_BAR();
    cur ^= 1;
  }
  for (int dt = 0; dt < 8; ++dt)
    for (int r = 0; r < 4; ++r){
      int qr = q0 + wq*16 + r4 + r;
      float o = acc[dt][r] / lrun[r];
      size_t ix = (size_t)qr * D_ + h*HD_ + dt*16 + lr;
      short a, b, c; split3(o, a, b, c);
      c0p[ix] = a; c1p[ix] = b; c2p[ix] = c;
    }
}

// ---------------- GEMM modes ----------------------------------------------
enum { M_QKV = 0, M_OPROJ = 1 };

// ------- Pipelined split GEMM (round-9 single register set) ----------------
template<int MODE>
__global__ __launch_bounds__(256) void gemm3_kernel(
    const short* __restrict__ A0, const short* __restrict__ A1, const short* __restrict__ A2,
    const float* __restrict__ Bw,
    const short* __restrict__ Bp0, const short* __restrict__ Bp1,
    const float* __restrict__ bias, const float* __restrict__ addsrc,
    float* __restrict__ outF,
    int K, int lda, int ldb, int ldo)
{
  __shared__ __attribute__((aligned(16))) short As[2][3][64][40];
  __shared__ __attribute__((aligned(16))) short Bs[2][2][64][40];

  int m0 = blockIdx.y * 64, n0 = blockIdx.x * 64;
  int tid = threadIdx.x, lane = tid & 63, wid = tid >> 6;
  int wm = wid >> 1, wn = wid & 1;
  int lr = lane & 15, kq8 = (lane >> 4) * 8;

  f32x4 acc[2][2];
  for (int i = 0; i < 2; ++i)
    for (int j = 0; j < 2; ++j) acc[i][j] = f32x4{0.f,0.f,0.f,0.f};

  int arow = tid >> 2, ac = (tid & 3) * 8;
  const short* aP0 = A0 + (size_t)(m0 + arow) * lda + ac;
  const short* aP1 = A1 + (size_t)(m0 + arow) * lda + ac;
  const short* aP2 = A2 + (size_t)(m0 + arow) * lda + ac;
  int bn = tid & 63, bk0 = (tid >> 6) * 8;
  const float* bP  = Bw  ? (Bw + n0 + bn) : nullptr;
  const short* bq0 = Bp0 ? (Bp0 + (size_t)(n0 + bn) * K) : nullptr;
  const short* bq1 = Bp1 ? (Bp1 + (size_t)(n0 + bn) * K) : nullptr;

  uint4 ar0, ar1, ar2; float br[8];
  uint4 pb0, pb1;

  auto LOAD = [&](int kt){
    ar0 = *(const uint4*)(aP0 + kt*32);
    ar1 = *(const uint4*)(aP1 + kt*32);
    ar2 = *(const uint4*)(aP2 + kt*32);
    if constexpr (MODE == M_QKV){
      const float* p = bP + (size_t)(kt*32 + bk0) * ldb;
      #pragma unroll
      for (int j = 0; j < 8; ++j) br[j] = p[(size_t)j * ldb];
    } else {
      pb0 = *(const uint4*)(bq0 + kt*32 + bk0);
      pb1 = *(const uint4*)(bq1 + kt*32 + bk0);
    }
  };
  auto STORE = [&](int buf){
    *(uint4*)&As[buf][0][arow][ac] = ar0;
    *(uint4*)&As[buf][1][arow][ac] = ar1;
    *(uint4*)&As[buf][2][arow][ac] = ar2;
    if constexpr (MODE == M_QKV){
      unsigned hh[4], mm[4];
      #pragma unroll
      for (int p = 0; p < 4; ++p){
        unsigned h = cvtpk(br[2*p], br[2*p+1]);
        mm[p] = cvtpk(br[2*p] - pk_lo(h), br[2*p+1] - pk_hi(h));
        hh[p] = h;
      }
      *(uint4*)&Bs[buf][0][bn][bk0] = mk4(hh[0],hh[1],hh[2],hh[3]);
      *(uint4*)&Bs[buf][1][bn][bk0] = mk4(mm[0],mm[1],mm[2],mm[3]);
    } else {
      *(uint4*)&Bs[buf][0][bn][bk0] = pb0;
      *(uint4*)&Bs[buf][1][bn][bk0] = pb1;
    }
  };

  int NK = K / 32;
  LOAD(0); STORE(0);
  if (NK > 1) LOAD(1);
  LGKM0_BAR();

  int cur = 0;
  for (int kt = 0; kt < NK; ++kt){
    if (kt + 1 < NK){
      STORE(cur ^ 1);
      if (kt + 2 < NK) LOAD(kt + 2);
    }
    bf16x8 aH[2], aM[2], aL[2];
    #pragma unroll
    for (int mt = 0; mt < 2; ++mt){
      aH[mt] = *(const bf16x8*)&As[cur][0][wm*32 + mt*16 + lr][kq8];
      aM[mt] = *(const bf16x8*)&As[cur][1][wm*32 + mt*16 + lr][kq8];
      aL[mt] = *(const bf16x8*)&As[cur][2][wm*32 + mt*16 + lr][kq8];
    }
    #pragma unroll
    for (int nt = 0; nt < 2; ++nt){
      bf16x8 bH = *(const bf16x8*)&Bs[cur][0][wn*32 + nt*16 + lr][kq8];
      bf16x8 bM = *(const bf16x8*)&Bs[cur][1][wn*32 + nt*16 + lr][kq8];
      #pragma unroll
      for (int mt = 0; mt < 2; ++mt){
        f32x4 a = acc[mt][nt];
        a = mfma16(aH[mt], bH, a);
        a = mfma16(aH[mt], bM, a);
        a = mfma16(aM[mt], bH, a);
        a = mfma16(aM[mt], bM, a);
        a = mfma16(aL[mt], bH, a);
        acc[mt][nt] = a;
      }
    }
    LGKM0_BAR();
    cur ^= 1;
  }

  for (int mt = 0; mt < 2; ++mt)
    for (int nt = 0; nt < 2; ++nt)
      for (int r = 0; r < 4; ++r){
        int mrow = m0 + wm*32 + mt*16 + (lane >> 4)*4 + r;
        int col  = n0 + wn*32 + nt*16 + lr;
        float v = acc[mt][nt][r];
        if constexpr (MODE == M_QKV){
          outF[(size_t)mrow * ldo + col] = v + bias[col];
        } else {
          outF[(size_t)mrow * ldo + col] = v + addsrc[(size_t)mrow * ldo + col];
        }
      }
}

// ------- Merged gate/up GEMM: BM=128, float4 B loads + XOR-swizzled Bs ------
__global__ __launch_bounds__(256) void gu_kernel(
    const short* __restrict__ x2b,
    const float* __restrict__ w_gate, const float* __restrict__ w_up,
    const float* __restrict__ sh_gu,
    short* __restrict__ gbuf, short* __restrict__ sbuf,
    const int* __restrict__ perm, const int* __restrict__ offE,
    const int* __restrict__ cntE)
{
  __shared__ __attribute__((aligned(16))) short As[2][128][40];
  __shared__ __attribute__((aligned(16))) short Bs[2][2][64][40];

  int z = blockIdx.z;
  bool SH = (z == E_);
  int N    = SH ? IS_ : IM_;
  int n0 = blockIdx.x * 64;
  if (n0 >= N) return;
  int mcnt  = SH ? T_ : cntE[z];
  int mbase = SH ? 0  : offE[z];
  int m0 = blockIdx.y * 128;
  if (m0 >= mcnt) return;
  int ldb = SH ? 2*IS_ : IM_;
  int ldo = SH ? IS_   : IM_;
  const float* Bg = SH ? sh_gu         : (w_gate + (size_t)z * D_ * IM_);
  const float* Bu = SH ? (sh_gu + IS_) : (w_up   + (size_t)z * D_ * IM_);
  short* outB = SH ? sbuf : gbuf;

  int tid = threadIdx.x, lane = tid & 63, wid = tid >> 6;
  int wm = wid >> 1, wn = wid & 1;
  int lr = lane & 15, kq8 = (lane >> 4) * 8;

  f32x4 acc0[4][2], acc1[4][2];
  #pragma unroll
  for (int i = 0; i < 4; ++i)
    for (int j = 0; j < 2; ++j){
      acc0[i][j] = f32x4{0.f,0.f,0.f,0.f};
      acc1[i][j] = f32x4{0.f,0.f,0.f,0.f};
    }

  int arow = tid >> 1, acol = (tid & 1) * 16;
  int aRowIdx;
  { int mr = m0 + arow;
    int mc = (mr < mcnt) ? mr : 0;
    aRowIdx = SH ? mc : perm[mbase + mc];
  }
  const short* aP = x2b + (size_t)aRowIdx * D_;

  // B staging: thread -> (kpair = (tid>>4)*2, n4 = (tid&15)*4), float4 loads
  int n4 = (tid & 15) * 4, kp2 = (tid >> 4) * 2;
  // swizzled dword index within 20-dword row: group g=(tid>>4)>>2 XOR (n>>2)&3
  int swg = ((((tid >> 4) >> 2) ^ ((tid & 15) & 3)) << 2) + ((tid >> 4) & 3);
  const float* bP0 = Bg + n0 + n4;
  const float* bP1 = Bu + n0 + n4;

  uint4 arA, arB;
  float4 g0, g1, u0, u1;

  auto LOAD = [&](int kt){
    const uint4* s = (const uint4*)(aP + kt*32 + acol);
    arA = s[0]; arB = s[1];
    const float* p0 = bP0 + (size_t)(kt*32 + kp2) * ldb;
    g0 = *(const float4*)p0;
    g1 = *(const float4*)(p0 + ldb);
    const float* p1 = bP1 + (size_t)(kt*32 + kp2) * ldb;
    u0 = *(const float4*)p1;
    u1 = *(const float4*)(p1 + ldb);
  };
  auto STORE = [&](int buf){
    *(uint4*)&As[buf][arow][acol]   = arA;
    *(uint4*)&As[buf][arow][acol+8] = arB;
    unsigned* r0 = (unsigned*)&Bs[buf][0][0][0];
    unsigned* r1 = (unsigned*)&Bs[buf][1][0][0];
    float ga[4] = {g0.x, g0.y, g0.z, g0.w};
    float gb[4] = {g1.x, g1.y, g1.z, g1.w};
    float ua[4] = {u0.x, u0.y, u0.z, u0.w};
    float ub[4] = {u1.x, u1.y, u1.z, u1.w};
    #pragma unroll
    for (int u = 0; u < 4; ++u){
      r0[(n4 + u) * 20 + swg] = cvtpk(ga[u], gb[u]);
      r1[(n4 + u) * 20 + swg] = cvtpk(ua[u], ub[u]);
    }
  };

  constexpr int NK = D_ / 32;   // 64
  LOAD(0); STORE(0);
  LOAD(1);
  LGKM0_BAR();

  int cur = 0;
  for (int kt = 0; kt < NK; ++kt){
    if (kt + 1 < NK){
      STORE(cur ^ 1);
      if (kt + 2 < NK) LOAD(kt + 2);
    }
    bf16x8 a[4];
    #pragma unroll
    for (int mt = 0; mt < 4; ++mt)
      a[mt] = *(const bf16x8*)&As[cur][wm*64 + mt*16 + lr][kq8];
    #pragma unroll
    for (int nt = 0; nt < 2; ++nt){
      int nrow = wn*32 + nt*16 + lr;
      int sc = (((kq8 >> 3) ^ ((nrow >> 2) & 3)) << 3);
      bf16x8 b0 = *(const bf16x8*)&Bs[cur][0][nrow][sc];
      bf16x8 b1 = *(const bf16x8*)&Bs[cur][1][nrow][sc];
      #pragma unroll
      for (int mt = 0; mt < 4; ++mt){
        acc0[mt][nt] = mfma16(a[mt], b0, acc0[mt][nt]);
        acc1[mt][nt] = mfma16(a[mt], b1, acc1[mt][nt]);
      }
    }
    LGKM0_BAR();
    cur ^= 1;
  }

  for (int mt = 0; mt < 4; ++mt)
    for (int nt = 0; nt < 2; ++nt)
      for (int r = 0; r < 4; ++r){
        int mrow = m0 + wm*64 + mt*16 + (lane >> 4)*4 + r;
        if (mrow >= mcnt) continue;
        int col = n0 + wn*32 + nt*16 + lr;
        float v = acc0[mt][nt][r];
        float u = acc1[mt][nt][r];
        float sv = v / (1.f + __expf(-v)) * u;
        outB[(size_t)(mbase + mrow) * ldo + col] = f2bf(sv);
      }
}

// ------- Merged down-proj GEMM: BM=128 + K-split + float4 B loads -----------
__global__ __launch_bounds__(256) void dn_kernel(
    const short* __restrict__ gbuf, const short* __restrict__ sbuf,
    const float* __restrict__ w_down, const float* __restrict__ sh_down,
    float* __restrict__ outF,
    const int* __restrict__ perm, const int* __restrict__ offE,
    const int* __restrict__ cntE, const float* __restrict__ wgt,
    const float* __restrict__ sig)
{
  __shared__ __attribute__((aligned(16))) short As[2][128][40];
  __shared__ __attribute__((aligned(16))) short Bs[2][64][40];

  int z = blockIdx.z;
  bool SH = (z >= 2*E_);
  int K, kbase, NK, mcnt, mbase;
  const float* Bq;
  const short* Ab;
  if (SH){
    int q = z - 2*E_;                 // 0..3
    K = IS_; kbase = q * (IS_/4); NK = (IS_/4)/32;   // 1408, 44 tiles
    mcnt = T_; mbase = 0;
    Bq = sh_down; Ab = sbuf;
  } else {
    int e = z >> 1, half = z & 1;
    K = IM_; kbase = half * (IM_/2); NK = (IM_/2)/32; // 704, 22 tiles
    mcnt = cntE[e]; mbase = offE[e];
    Bq = w_down + (size_t)e * IM_ * D_; Ab = gbuf;
  }
  int m0 = blockIdx.y * 128;
  if (m0 >= mcnt) return;
  int n0 = blockIdx.x * 64;

  int tid = threadIdx.x, lane = tid & 63, wid = tid >> 6;
  int wm = wid >> 1, wn = wid & 1;
  int lr = lane & 15, kq8 = (lane >> 4) * 8;

  f32x4 acc0[4][2];
  #pragma unroll
  for (int i = 0; i < 4; ++i)
    for (int j = 0; j < 2; ++j) acc0[i][j] = f32x4{0.f,0.f,0.f,0.f};

  int arow = tid >> 1, acol = (tid & 1) * 16;
  int mr = m0 + arow;
  int mc = (mr < mcnt) ? mr : 0;
  const short* aP = Ab + (size_t)(SH ? mc : (mbase + mc)) * K + kbase;

  int n4 = (tid & 15) * 4, kp2 = (tid >> 4) * 2;
  int swg = ((((tid >> 4) >> 2) ^ ((tid & 15) & 3)) << 2) + ((tid >> 4) & 3);
  const float* bP0 = Bq + (size_t)kbase * D_ + n0 + n4;

  uint4 arA, arB;
  float4 b0v, b1v;

  auto LOAD = [&](int kt){
    const uint4* s = (const uint4*)(aP + kt*32 + acol);
    arA = s[0]; arB = s[1];
    const float* p0 = bP0 + (size_t)(kt*32 + kp2) * D_;
    b0v = *(const float4*)p0;
    b1v = *(const float4*)(p0 + D_);
  };
  auto STORE = [&](int buf){
    *(uint4*)&As[buf][arow][acol]   = arA;
    *(uint4*)&As[buf][arow][acol+8] = arB;
    unsigned* r0 = (unsigned*)&Bs[buf][0][0];
    float ba[4] = {b0v.x, b0v.y, b0v.z, b0v.w};
    float bb[4] = {b1v.x, b1v.y, b1v.z, b1v.w};
    #pragma unroll
    for (int u = 0; u < 4; ++u)
      r0[(n4 + u) * 20 + swg] = cvtpk(ba[u], bb[u]);
  };

  LOAD(0); STORE(0);
  LOAD(1);
  LGKM0_BAR();

  int cur = 0;
  for (int kt = 0; kt < NK; ++kt){
    if (kt + 1 < NK){
      STORE(cur ^ 1);
      if (kt + 2 < NK) LOAD(kt + 2);
    }
    bf16x8 a[4];
    #pragma unroll
    for (int mt = 0; mt < 4; ++mt)
      a[mt] = *(const bf16x8*)&As[cur][wm*64 + mt*16 + lr][kq8];
    #pragma unroll
    for (int nt = 0; nt < 2; ++nt){
      int nrow = wn*32 + nt*16 + lr;
      int sc = (((kq8 >> 3) ^ ((nrow >> 2) & 3)) << 3);
      bf16x8 b0 = *(const bf16x8*)&Bs[cur][nrow][sc];
      #pragma unroll
      for (int mt = 0; mt < 4; ++mt)
        acc0[mt][nt] = mfma16(a[mt], b0, acc0[mt][nt]);
    }
    LGKM0_BAR();
    cur ^= 1;
  }

  for (int mt = 0; mt < 4; ++mt)
    for (int nt = 0; nt < 2; ++nt)
      for (int r = 0; r < 4; ++r){
        int mrow = m0 + wm*64 + mt*16 + (lane >> 4)*4 + r;
        if (mrow >= mcnt) continue;
        int col = n0 + wn*32 + nt*16 + lr;
        float v = acc0[mt][nt][r];
        if (SH){
          atomicAdd(&outF[(size_t)mrow * D_ + col], sig[mrow] * v);
        } else {
          int tk = perm[mbase + mrow];
          atomicAdd(&outF[(size_t)tk * D_ + col], v * wgt[mbase + mrow]);
        }
      }
}

// ---------------- Router ---------------------------------------------------
__global__ __launch_bounds__(256) void router_kernel(
    const float* __restrict__ x2f, const float* __restrict__ rw,
    const float* __restrict__ seg, int* __restrict__ te, float* __restrict__ tw,
    float* __restrict__ sig, int* __restrict__ cnt)
{
  int t = blockIdx.x, tid = threadIdx.x, lane = tid & 63, w = tid >> 6;
  const float* xr = x2f + (size_t)t * D_;
  float a0 = 0.f, a1 = 0.f, a2 = 0.f, a3 = 0.f, ag = 0.f;
  for (int j = 0; j < 32; ++j){
    int d = lane + 64*j;
    float xv = xr[d];
    const float* rp = rw + (size_t)d * E_ + w*4;
    a0 += xv * rp[0]; a1 += xv * rp[1]; a2 += xv * rp[2]; a3 += xv * rp[3];
    ag += xv * seg[d];
  }
  for (int o = 32; o; o >>= 1){
    a0 += __shfl_xor(a0, o, 64); a1 += __shfl_xor(a1, o, 64);
    a2 += __shfl_xor(a2, o, 64); a3 += __shfl_xor(a3, o, 64);
    ag += __shfl_xor(ag, o, 64);
  }
  __shared__ float lg[16];
  __shared__ float sgv;
  if (lane == 0){
    lg[w*4+0] = a0; lg[w*4+1] = a1; lg[w*4+2] = a2; lg[w*4+3] = a3;
    if (w == 0) sgv = ag;
  }
  __syncthreads();
  if (tid == 0){
    int e0 = 0; float v0 = lg[0];
    for (int ee = 1; ee < 16; ++ee) if (lg[ee] > v0){ v0 = lg[ee]; e0 = ee; }
    int e1 = -1; float v1 = -3e38f;
    for (int ee = 0; ee < 16; ++ee){
      if (ee == e0) continue;
      if (lg[ee] > v1){ v1 = lg[ee]; e1 = ee; }
    }
    float w0 = 1.f / (1.f + expf(v1 - v0));
    te[2*t] = e0; te[2*t+1] = e1;
    tw[2*t] = w0; tw[2*t+1] = 1.f - w0;
    atomicAdd(&cnt[e0], 1); atomicAdd(&cnt[e1], 1);
    sig[t] = 1.f / (1.f + expf(-sgv));
  }
}

__global__ void prefix_kernel(const int* __restrict__ cnt, int* __restrict__ offE,
                              int* __restrict__ cursor)
{
  if (threadIdx.x == 0){
    int s = 0;
    for (int e = 0; e < 16; ++e){ offE[e] = s; s += cnt[e]; }
  }
  if (threadIdx.x < 16) cursor[threadIdx.x] = 0;
}

__global__ __launch_bounds__(256) void scatter_kernel(
    const int* __restrict__ te, const float* __restrict__ tw,
    const int* __restrict__ offE, int* __restrict__ cursor,
    int* __restrict__ perm, float* __restrict__ wgt)
{
  int t = blockIdx.x * 256 + threadIdx.x;
  if (t >= T_) return;
  for (int i = 0; i < 2; ++i){
    int e = te[2*t + i];
    int pos = offE[e] + atomicAdd(&cursor[e], 1);
    perm[pos] = t; wgt[pos] = tw[2*t + i];
  }
}

// ---------------------------------------------------------------------------
extern "C" void kernel_launch(void* const* d_in, const int* in_sizes, int n_in,
                              void* d_out, int out_size, void* d_ws, size_t ws_size,
                              hipStream_t stream)
{
  const int*   positions = (const int*)  d_in[0];
  const float* hidden    = (const float*)d_in[1];
  const float* ln1       = (const float*)d_in[2];
  const float* ln2       = (const float*)d_in[3];
  const float* qkv_w     = (const float*)d_in[4];
  const float* qkv_b     = (const float*)d_in[5];
  const float* o_w       = (const float*)d_in[6];
  const float* router_w  = (const float*)d_in[7];
  const float* w_gate    = (const float*)d_in[8];
  const float* w_up      = (const float*)d_in[9];
  const float* w_down    = (const float*)d_in[10];
  const float* sh_gu     = (const float*)d_in[11];
  const float* sh_down   = (const float*)d_in[12];
  const float* sh_eg     = (const float*)d_in[13];

  float* out_hidden = (float*)d_out;
  float* out_resid  = (float*)d_out + (size_t)T_ * D_;

  char* wp = (char*)d_ws;
  auto alloc = [&](size_t b){ char* p = wp; wp += (b + 255) & ~(size_t)255; return p; };

  float* qkv  = (float*)alloc((size_t)T_ * 3*D_ * 4);   // 24 MB
  short* x1h  = (short*)alloc((size_t)T_ * D_ * 2);     // 12 MB (3 planes)
  short* x1m  = (short*)alloc((size_t)T_ * D_ * 2);
  short* x1l  = (short*)alloc((size_t)T_ * D_ * 2);
  short* Kp0  = (short*)alloc((size_t)T_ * D_ * 2);     // 16 MB (K/V planes)
  short* Kp1  = (short*)alloc((size_t)T_ * D_ * 2);
  short* Vp0  = (short*)alloc((size_t)T_ * D_ * 2);
  short* Vp1  = (short*)alloc((size_t)T_ * D_ * 2);
  float* cst  = (float*)alloc((size_t)T_ * 64 * 4);
  float* snt  = (float*)alloc((size_t)T_ * 64 * 4);
  int*   te   = (int*)  alloc(2*T_*4);
  float* tw   = (float*)alloc(2*T_*4);
  float* sig  = (float*)alloc(T_*4);
  int*   cnt    = (int*)alloc(256);
  int*   offE   = (int*)alloc(256);
  int*   cursor = (int*)alloc(256);
  int*   perm = (int*)  alloc(2*T_*4);
  float* wgt  = (float*)alloc(2*T_*4);

  // aliases (lifetimes disjoint):
  short* ctxh = x1h;                                    // after QKV GEMM
  short* ctxm = x1m;
  short* ctxl = x1l;
  float* x2f  = qkv;                                    // after attn
  short* sbuf = (short*)((char*)qkv + (size_t)8388608); // after attn
  short* gbuf = (short*)x1h;                            // after OPROJ
  short* x2b  = (short*)((char*)x1h + (size_t)5767168); // after OPROJ
  short* Wo0  = Kp0;                                    // after attn
  short* Wo1  = Vp0;                                    // after attn

  hipMemsetAsync(cnt, 0, 64, stream);
  hipMemsetAsync(out_hidden, 0, (size_t)T_ * D_ * 4, stream);

  sctab_kernel<<<(T_*64)/256, 256, 0, stream>>>(positions, cst, snt);

  rms_kernel<<<T_, 256, 0, stream>>>(hidden, ln1, x1h, x1m, x1l, nullptr, nullptr);

  gemm3_kernel<M_QKV><<<dim3(96, 16), 256, 0, stream>>>(
      x1h, x1m, x1l, qkv_w, nullptr, nullptr, qkv_b, nullptr, qkv,
      D_, D_, 3*D_, 3*D_);

  prepk_kernel<<<(T_*H_*8)/256, 256, 0, stream>>>(qkv, cst, snt, Kp0, Kp1);
  prepv_kernel<<<dim3(16, 16), 256, 0, stream>>>(qkv, Vp0, Vp1);

  attn_kernel<<<dim3(16, 32), 128, 0, stream>>>(
      qkv, cst, snt, Kp0, Kp1, Vp0, Vp1, ctxh, ctxm, ctxl);

  prepw_kernel<<<dim3(32, 32), 256, 0, stream>>>(o_w, Wo0, Wo1);

  gemm3_kernel<M_OPROJ><<<dim3(32, 16), 256, 0, stream>>>(
      ctxh, ctxm, ctxl, nullptr, Wo0, Wo1, nullptr, hidden, out_resid,
      D_, D_, D_, D_);

  rms_kernel<<<T_, 256, 0, stream>>>(out_resid, ln2, nullptr, nullptr, nullptr, x2b, x2f);

  router_kernel<<<T_, 256, 0, stream>>>(x2f, router_w, sh_eg, te, tw, sig, cnt);
  prefix_kernel<<<1, 64, 0, stream>>>(cnt, offE, cursor);
  scatter_kernel<<<4, 256, 0, stream>>>(te, tw, offE, cursor, perm, wgt);

  gu_kernel<<<dim3(88, 8, 17), 256, 0, stream>>>(
      x2b, w_gate, w_up, sh_gu, gbuf, sbuf, perm, offE, cnt);

  dn_kernel<<<dim3(32, 8, 36), 256, 0, stream>>>(
      gbuf, sbuf, w_down, sh_down, out_hidden, perm, offE, cnt, wgt, sig);

  (void)in_sizes; (void)n_in; (void)out_size; (void)ws_size;
}